// Round 1
// baseline (378.938 us; speedup 1.0000x reference)
//
#include <hip/hip_runtime.h>

// Problem constants (fixed by setup_inputs): B=4, H=8, L=1024, D=64, QDIM=512.
#define QD 512
#define NW (512*512)

typedef __attribute__((ext_vector_type(8))) short bf16x8;  // 8 bf16 = 4 VGPR
typedef __attribute__((ext_vector_type(4))) float f32x4;

#define MFMA16(a,b,c) __builtin_amdgcn_mfma_f32_16x16x32_bf16((a),(b),(c),0,0,0)

static __device__ __forceinline__ short f2bf(float f) {  // RNE float->bf16
  unsigned u = __float_as_uint(f);
  u += 0x7fffu + ((u >> 16) & 1u);
  return (short)(u >> 16);
}
static __device__ __forceinline__ float bf2f(short s) {
  return __uint_as_float(((unsigned)(unsigned short)s) << 16);
}

// ---------------- K0: pre-convert weights to bf16 hi/lo ----------------
__global__ __launch_bounds__(256) void k_wconv(
    const float* __restrict__ wq, const float* __restrict__ wk,
    const float* __restrict__ wv, const float* __restrict__ wp,
    short* __restrict__ W6, short* __restrict__ WPH) {
  int i = blockIdx.x * 256 + threadIdx.x;
  if (i < 3 * NW) {
    int which = i / NW, j = i - which * NW;
    const float* src = which == 0 ? wq : (which == 1 ? wk : wv);
    float f = src[j];
    short h = f2bf(f);
    short l = f2bf(f - bf2f(h));
    W6[(size_t)which * 2 * NW + j] = h;
    W6[(size_t)which * 2 * NW + NW + j] = l;
  } else {
    int j = i - 3 * NW;
    if (j < 64 * QD) WPH[j] = f2bf(wp[j]);
  }
}

// ---------------- K1: fused Q/K/V projections (split-bf16 MFMA) ----------------
// X(4096x512) @ W^T(512x512) + bias. out col n = h*64+d.
// Q,K -> hi/lo bf16 in [b,h,l,d]; V -> bf16 in [b,h,d,l] (transposed for k_ctx).
__global__ __launch_bounds__(256) void k_proj(
    const float* __restrict__ q, const float* __restrict__ k, const float* __restrict__ v,
    const float* __restrict__ bq, const float* __restrict__ bk, const float* __restrict__ bv,
    const short* __restrict__ W6,
    short* __restrict__ QsH, short* __restrict__ QsL,
    short* __restrict__ KsH, short* __restrict__ KsL,
    short* __restrict__ Vt) {
  const int t = blockIdx.z;
  const float* X = t == 0 ? q : (t == 1 ? k : v);
  const float* bias = t == 0 ? bq : (t == 1 ? bk : bv);
  const short* WH = W6 + (size_t)t * 2 * NW;
  const short* WL = WH + NW;
  const int lane = threadIdx.x & 63, w = threadIdx.x >> 6;
  const int col = lane & 15, g = lane >> 4;
  const int m0 = blockIdx.y * 64 + w * 16;  // row block (b*1024+l)
  const int n0 = blockIdx.x * 64;           // h = blockIdx.x

  f32x4 zero = {0.f, 0.f, 0.f, 0.f};
  f32x4 acc[4] = {zero, zero, zero, zero};

  for (int kc = 0; kc < 16; ++kc) {
    const float* xp = X + (size_t)(m0 + col) * QD + kc * 32 + g * 8;
    f32x4 x0 = *(const f32x4*)xp;
    f32x4 x1 = *(const f32x4*)(xp + 4);
    bf16x8 ah, al;
#pragma unroll
    for (int j = 0; j < 4; ++j) {
      short h0 = f2bf(x0[j]); short h1 = f2bf(x1[j]);
      ah[j] = h0; ah[j + 4] = h1;
      al[j] = f2bf(x0[j] - bf2f(h0));
      al[j + 4] = f2bf(x1[j] - bf2f(h1));
    }
#pragma unroll
    for (int nt = 0; nt < 4; ++nt) {
      size_t woff = (size_t)(n0 + nt * 16 + col) * QD + kc * 32 + g * 8;
      bf16x8 bh = *(const bf16x8*)(WH + woff);
      bf16x8 bl = *(const bf16x8*)(WL + woff);
      acc[nt] = MFMA16(ah, bh, acc[nt]);  // hi*hi
      acc[nt] = MFMA16(al, bh, acc[nt]);  // lo_x*hi_w
      acc[nt] = MFMA16(ah, bl, acc[nt]);  // hi_x*lo_w
    }
  }

#pragma unroll
  for (int nt = 0; nt < 4; ++nt) {
    float bias_v = bias[n0 + nt * 16 + col];
    int d = nt * 16 + col;
#pragma unroll
    for (int r = 0; r < 4; ++r) {
      int m = m0 + g * 4 + r;
      int b = m >> 10, l = m & 1023;
      float val = acc[nt][r] + bias_v;
      if (t < 2) {
        size_t idx = (((size_t)b * 8 + blockIdx.x) * 1024 + l) * 64 + d;
        short h = f2bf(val);
        short lo = f2bf(val - bf2f(h));
        if (t == 0) { QsH[idx] = h; QsL[idx] = lo; }
        else        { KsH[idx] = h; KsL[idx] = lo; }
      } else {
        size_t idx = (((size_t)b * 8 + blockIdx.x) * 64 + d) * 1024 + l;
        Vt[idx] = f2bf(val);
      }
    }
  }
}

// ---------------- K2: scores + softmax + attn write ----------------
// Swapped mfma(K,Q): tile D[row=k][col=q]; softmax over k is lane-local per q-col.
// Pass 1: online max/sum (3-term split MFMA). Pass 2: recompute, write attn fp32.
__global__ __launch_bounds__(256) void k_attn(
    const short* __restrict__ QsH, const short* __restrict__ QsL,
    const short* __restrict__ KsH, const short* __restrict__ KsL,
    float* __restrict__ attn) {
  const int lane = threadIdx.x & 63, w = threadIdx.x >> 6;
  const int col = lane & 15, g = lane >> 4;
  const int bh = blockIdx.y;
  const int q0 = blockIdx.x * 128 + w * 32;  // 32 q-rows per wave (2 col-tiles)
  const size_t base = (size_t)bh * 1024 * 64;

  bf16x8 qh[2][2], ql[2][2];
#pragma unroll
  for (int c = 0; c < 2; ++c) {
    size_t qoff = base + (size_t)(q0 + c * 16 + col) * 64 + g * 8;
    qh[c][0] = *(const bf16x8*)(QsH + qoff);
    qh[c][1] = *(const bf16x8*)(QsH + qoff + 32);
    ql[c][0] = *(const bf16x8*)(QsL + qoff);
    ql[c][1] = *(const bf16x8*)(QsL + qoff + 32);
  }

  float mx[2] = {-1e30f, -1e30f}, sum[2] = {0.f, 0.f};
  f32x4 zero = {0.f, 0.f, 0.f, 0.f};

  // ---- pass 1: stats ----
  for (int kc = 0; kc < 64; ++kc) {
    size_t koff = base + (size_t)(kc * 16 + col) * 64 + g * 8;
    bf16x8 kh0 = *(const bf16x8*)(KsH + koff);
    bf16x8 kh1 = *(const bf16x8*)(KsH + koff + 32);
    bf16x8 kl0 = *(const bf16x8*)(KsL + koff);
    bf16x8 kl1 = *(const bf16x8*)(KsL + koff + 32);
#pragma unroll
    for (int c = 0; c < 2; ++c) {
      f32x4 S = zero;
      S = MFMA16(kh0, qh[c][0], S);
      S = MFMA16(kh1, qh[c][1], S);
      S = MFMA16(kl0, qh[c][0], S);
      S = MFMA16(kl1, qh[c][1], S);
      S = MFMA16(kh0, ql[c][0], S);
      S = MFMA16(kh1, ql[c][1], S);
      float v0 = S[0] * 0.5f, v1 = S[1] * 0.5f, v2 = S[2] * 0.5f, v3 = S[3] * 0.5f;
      float mloc = fmaxf(fmaxf(v0, v1), fmaxf(v2, v3));
      if (mloc > mx[c]) { sum[c] *= __expf(mx[c] - mloc); mx[c] = mloc; }
      sum[c] += __expf(v0 - mx[c]) + __expf(v1 - mx[c]) +
                __expf(v2 - mx[c]) + __expf(v3 - mx[c]);
    }
  }
  // combine the 4 lane-groups (each holds 1/4 of the k range for this q-col)
#pragma unroll
  for (int c = 0; c < 2; ++c) {
    for (int off = 16; off < 64; off <<= 1) {
      float mo = __shfl_xor(mx[c], off);
      float so = __shfl_xor(sum[c], off);
      float mn = fmaxf(mx[c], mo);
      sum[c] = sum[c] * __expf(mx[c] - mn) + so * __expf(mo - mn);
      mx[c] = mn;
    }
  }
  float inv[2] = {1.f / sum[0], 1.f / sum[1]};

  // ---- pass 2: recompute + write ----
  float* ab = attn + (size_t)bh * 1024 * 1024;
  for (int kc = 0; kc < 64; ++kc) {
    size_t koff = base + (size_t)(kc * 16 + col) * 64 + g * 8;
    bf16x8 kh0 = *(const bf16x8*)(KsH + koff);
    bf16x8 kh1 = *(const bf16x8*)(KsH + koff + 32);
    bf16x8 kl0 = *(const bf16x8*)(KsL + koff);
    bf16x8 kl1 = *(const bf16x8*)(KsL + koff + 32);
#pragma unroll
    for (int c = 0; c < 2; ++c) {
      f32x4 S = zero;
      S = MFMA16(kh0, qh[c][0], S);
      S = MFMA16(kh1, qh[c][1], S);
      S = MFMA16(kl0, qh[c][0], S);
      S = MFMA16(kl1, qh[c][1], S);
      S = MFMA16(kh0, ql[c][0], S);
      S = MFMA16(kh1, ql[c][1], S);
      f32x4 o;
#pragma unroll
      for (int r = 0; r < 4; ++r) o[r] = __expf(S[r] * 0.5f - mx[c]) * inv[c];
      *(f32x4*)(ab + (size_t)(q0 + c * 16 + col) * 1024 + kc * 16 + g * 4) = o;
    }
  }
}

// ---------------- K3: context = attn^T @ V (sum over q) ----------------
// D[row=k][col=d]; a-frag reads attn[q][k] (16-lane groups hit 64B-contiguous),
// b-frag reads Vt[b,h,d,q] contiguous. ctx stored bf16 as (b*1024+k, h*64+d).
__global__ __launch_bounds__(256) void k_ctx(
    const float* __restrict__ attn, const short* __restrict__ Vt,
    short* __restrict__ ctx) {
  const int lane = threadIdx.x & 63, w = threadIdx.x >> 6;
  const int col = lane & 15, g = lane >> 4;
  const int bh = blockIdx.y;
  const int k0 = blockIdx.x * 64 + w * 16;
  const float* ab = attn + (size_t)bh * 1024 * 1024;
  const short* vb = Vt + (size_t)bh * 64 * 1024;

  f32x4 zero = {0.f, 0.f, 0.f, 0.f};
  f32x4 acc[4] = {zero, zero, zero, zero};

  for (int qc = 0; qc < 32; ++qc) {
    const float* ap = ab + (size_t)(qc * 32 + g * 8) * 1024 + k0 + col;
    bf16x8 af;
#pragma unroll
    for (int j = 0; j < 8; ++j) af[j] = f2bf(ap[(size_t)j * 1024]);
#pragma unroll
    for (int nt = 0; nt < 4; ++nt) {
      bf16x8 bfv = *(const bf16x8*)(vb + (size_t)(nt * 16 + col) * 1024 + qc * 32 + g * 8);
      acc[nt] = MFMA16(af, bfv, acc[nt]);
    }
  }
  int b = bh >> 3, h = bh & 7;
#pragma unroll
  for (int nt = 0; nt < 4; ++nt)
#pragma unroll
    for (int r = 0; r < 4; ++r) {
      int kk = k0 + g * 4 + r;
      ctx[((size_t)(b * 1024 + kk)) * 512 + h * 64 + nt * 16 + col] = f2bf(acc[nt][r]);
    }
}

// ---------------- K4: output = ctx @ wp^T + bp ----------------
__global__ __launch_bounds__(256) void k_out(
    const short* __restrict__ ctx, const short* __restrict__ WPH,
    const float* __restrict__ bp, float* __restrict__ out) {
  const int lane = threadIdx.x & 63, w = threadIdx.x >> 6;
  const int col = lane & 15, g = lane >> 4;
  const int m0 = blockIdx.x * 64 + w * 16;

  f32x4 zero = {0.f, 0.f, 0.f, 0.f};
  f32x4 acc[4] = {zero, zero, zero, zero};

  for (int kc = 0; kc < 16; ++kc) {
    bf16x8 a = *(const bf16x8*)(ctx + (size_t)(m0 + col) * 512 + kc * 32 + g * 8);
#pragma unroll
    for (int nt = 0; nt < 4; ++nt) {
      bf16x8 bfr = *(const bf16x8*)(WPH + (size_t)(nt * 16 + col) * 512 + kc * 32 + g * 8);
      acc[nt] = MFMA16(a, bfr, acc[nt]);
    }
  }
#pragma unroll
  for (int nt = 0; nt < 4; ++nt) {
    float bias = bp[nt * 16 + col];
#pragma unroll
    for (int r = 0; r < 4; ++r)
      out[(size_t)(m0 + g * 4 + r) * 64 + nt * 16 + col] = acc[nt][r] + bias;
  }
}

extern "C" void kernel_launch(void* const* d_in, const int* in_sizes, int n_in,
                              void* d_out, int out_size, void* d_ws, size_t ws_size,
                              hipStream_t stream) {
  const float* q  = (const float*)d_in[0];
  const float* k  = (const float*)d_in[1];
  const float* v  = (const float*)d_in[2];
  const float* wq = (const float*)d_in[3];
  const float* bq = (const float*)d_in[4];
  const float* wk = (const float*)d_in[5];
  const float* bk = (const float*)d_in[6];
  const float* wv = (const float*)d_in[7];
  const float* bv = (const float*)d_in[8];
  const float* wp = (const float*)d_in[9];
  const float* bp = (const float*)d_in[10];

  float* out  = (float*)d_out;            // (4,1024,64) = 262144 floats
  float* attn = out + 262144;             // (4,8,1024,1024)

  // workspace layout (shorts): 6 arrays of 2,097,152 + weights (total ~28.4 MB)
  short* S = (short*)d_ws;
  const size_t E = 2097152;
  short* QsH = S;
  short* QsL = S + E;
  short* KsH = S + 2 * E;
  short* KsL = S + 3 * E;
  short* Vt  = S + 4 * E;
  short* ctx = S + 5 * E;
  short* W6  = S + 6 * E;                 // [3][2][512*512]
  short* WPH = W6 + 6 * (size_t)NW;       // [64][512]

  k_wconv<<<dim3(3200), dim3(256), 0, stream>>>(wq, wk, wv, wp, W6, WPH);
  k_proj <<<dim3(8, 64, 3), dim3(256), 0, stream>>>(q, k, v, bq, bk, bv, W6,
                                                    QsH, QsL, KsH, KsL, Vt);
  k_attn <<<dim3(8, 32), dim3(256), 0, stream>>>(QsH, QsL, KsH, KsL, attn);
  k_ctx  <<<dim3(16, 32), dim3(256), 0, stream>>>(attn, Vt, ctx);
  k_out  <<<dim3(64), dim3(256), 0, stream>>>(ctx, WPH, bp, out);
}

// Round 2
// 367.563 us; speedup vs baseline: 1.0309x; 1.0309x over previous
//
#include <hip/hip_runtime.h>

// B=4, H=8, L=1024, D=64, QDIM=512.
#define QD 512
#define NW (512*512)  // 262144 elements per weight matrix

typedef __attribute__((ext_vector_type(8))) short bf16x8;  // 8 bf16
typedef __attribute__((ext_vector_type(4))) float f32x4;

#define MFMA16(a,b,c) __builtin_amdgcn_mfma_f32_16x16x32_bf16((a),(b),(c),0,0,0)

static __device__ __forceinline__ short f2bf(float f) {  // RNE float->bf16
  unsigned u = __float_as_uint(f);
  u += 0x7fffu + ((u >> 16) & 1u);
  return (short)(u >> 16);
}
static __device__ __forceinline__ float bf2f(short s) {
  return __uint_as_float(((unsigned)(unsigned short)s) << 16);
}

#define GL2LDS16(g, l)                                                        \
  __builtin_amdgcn_global_load_lds(                                           \
      (const __attribute__((address_space(1))) unsigned int*)(g),             \
      (__attribute__((address_space(3))) unsigned int*)(l), 16, 0, 0)

// ---------------- K0: weights -> bf16 (hi/lo for wq,wk; hi for wv,wp) -------
__global__ __launch_bounds__(256) void k_wconv(
    const float* __restrict__ wq, const float* __restrict__ wk,
    const float* __restrict__ wv, const float* __restrict__ wp,
    short* __restrict__ W, short* __restrict__ WPH) {
  int i = blockIdx.x * 256 + threadIdx.x;
  if (i < NW) {
    float f = wq[i]; short h = f2bf(f);
    W[i] = h; W[NW + i] = f2bf(f - bf2f(h));
  } else if (i < 2 * NW) {
    int j = i - NW;
    float f = wk[j]; short h = f2bf(f);
    W[2 * NW + j] = h; W[3 * NW + j] = f2bf(f - bf2f(h));
  } else if (i < 3 * NW) {
    int j = i - 2 * NW;
    W[4 * NW + j] = f2bf(wv[j]);
  } else {
    int j = i - 3 * NW;
    if (j < 64 * QD) WPH[j] = f2bf(wp[j]);
  }
}

// ---------------- K0b: activations -> bf16 (hi/lo for q,k; hi for v) --------
__global__ __launch_bounds__(256) void k_xconv(
    const float* __restrict__ q, const float* __restrict__ k, const float* __restrict__ v,
    short* __restrict__ XqH, short* __restrict__ XqL,
    short* __restrict__ XkH, short* __restrict__ XkL, short* __restrict__ XvH) {
  int i = blockIdx.x * 256 + threadIdx.x;   // one group of 8 floats
  int t = i >> 18;                          // 262144 groups per tensor
  int j = i & 0x3FFFF;
  const float* src = t == 0 ? q : (t == 1 ? k : v);
  f32x4 x0 = *(const f32x4*)(src + (size_t)j * 8);
  f32x4 x1 = *(const f32x4*)(src + (size_t)j * 8 + 4);
  bf16x8 H, L;
#pragma unroll
  for (int jj = 0; jj < 4; ++jj) {
    short h0 = f2bf(x0[jj]); H[jj] = h0; L[jj] = f2bf(x0[jj] - bf2f(h0));
    short h1 = f2bf(x1[jj]); H[jj + 4] = h1; L[jj + 4] = f2bf(x1[jj] - bf2f(h1));
  }
  if (t == 0)      { *(bf16x8*)(XqH + (size_t)j * 8) = H; *(bf16x8*)(XqL + (size_t)j * 8) = L; }
  else if (t == 1) { *(bf16x8*)(XkH + (size_t)j * 8) = H; *(bf16x8*)(XkL + (size_t)j * 8) = L; }
  else             { *(bf16x8*)(XvH + (size_t)j * 8) = H; }
}

// ---------------- K1: projection GEMM, LDS-staged, split-bf16 ---------------
// C(4096x512) = X @ W^T + bias. 64x64 tile, BK=32, 4 waves (2x2), 16B-slot
// XOR swizzle (pre-swizzled global source + swizzled ds_read, both-sides).
// mode 0: out hi/lo to [b,h,l,d]; mode 1 (V): out bf16 to [b,h,d,l].
__global__ __launch_bounds__(256) void k_proj(
    const short* __restrict__ XH, const short* __restrict__ XL,
    const short* __restrict__ WH, const short* __restrict__ WL,
    const float* __restrict__ bias,
    short* __restrict__ outH, short* __restrict__ outL,
    short* __restrict__ Vt, int mode) {
  __shared__ short Ah[64 * 32], Al[64 * 32], Bh[64 * 32], Bl[64 * 32];
  const int tid = threadIdx.x;
  const int lane = tid & 63;
  const int col = lane & 15, g = lane >> 4;
  const int w = tid >> 6, wr = w >> 1, wc = w & 1;
  const int h = blockIdx.x;            // n0 = h*64 (one head per block)
  const int m0 = blockIdx.y * 64;
  // staging map: thread tid covers LDS row srow = tid/4, 16B slot tid%4;
  // source column is XOR-swizzled so reads can deswizzle.
  const int srow = tid >> 2;
  const int scol = ((tid & 3) ^ (srow & 3)) * 8;  // element offset in row
  const size_t xrow = (size_t)(m0 + srow) * QD + scol;
  const size_t wrow = (size_t)(h * 64 + srow) * QD + scol;

  f32x4 zero = {0.f, 0.f, 0.f, 0.f};
  f32x4 acc[2][2] = {{zero, zero}, {zero, zero}};

  for (int kc = 0; kc < 16; ++kc) {
    const int kb = kc * 32;
    GL2LDS16(XH + xrow + kb, &Ah[tid * 8]);
    GL2LDS16(WH + wrow + kb, &Bh[tid * 8]);
    if (mode == 0) {
      GL2LDS16(XL + xrow + kb, &Al[tid * 8]);
      GL2LDS16(WL + wrow + kb, &Bl[tid * 8]);
    }
    __syncthreads();

    bf16x8 a_h[2], a_l[2], b_h[2], b_l[2];
#pragma unroll
    for (int mt = 0; mt < 2; ++mt) {
      int rowa = wr * 32 + mt * 16 + col;
      int off = rowa * 32 + ((g ^ (rowa & 3)) * 8);
      a_h[mt] = *(const bf16x8*)&Ah[off];
      if (mode == 0) a_l[mt] = *(const bf16x8*)&Al[off];
    }
#pragma unroll
    for (int nt = 0; nt < 2; ++nt) {
      int rowb = wc * 32 + nt * 16 + col;
      int off = rowb * 32 + ((g ^ (rowb & 3)) * 8);
      b_h[nt] = *(const bf16x8*)&Bh[off];
      if (mode == 0) b_l[nt] = *(const bf16x8*)&Bl[off];
    }
#pragma unroll
    for (int mt = 0; mt < 2; ++mt)
#pragma unroll
      for (int nt = 0; nt < 2; ++nt) {
        acc[mt][nt] = MFMA16(a_h[mt], b_h[nt], acc[mt][nt]);
        if (mode == 0) {
          acc[mt][nt] = MFMA16(a_l[mt], b_h[nt], acc[mt][nt]);
          acc[mt][nt] = MFMA16(a_h[mt], b_l[nt], acc[mt][nt]);
        }
      }
    __syncthreads();
  }

#pragma unroll
  for (int nt = 0; nt < 2; ++nt) {
    int d = wc * 32 + nt * 16 + col;
    float bias_v = bias[h * 64 + d];
#pragma unroll
    for (int mt = 0; mt < 2; ++mt)
#pragma unroll
      for (int r = 0; r < 4; ++r) {
        int m = m0 + wr * 32 + mt * 16 + g * 4 + r;
        int b = m >> 10, l = m & 1023;
        float val = acc[mt][nt][r] + bias_v;
        if (mode == 0) {
          size_t idx = (((size_t)b * 8 + h) * 1024 + l) * 64 + d;
          short hh = f2bf(val);
          outH[idx] = hh;
          outL[idx] = f2bf(val - bf2f(hh));
        } else {
          Vt[(((size_t)b * 8 + h) * 64 + d) * 1024 + l] = f2bf(val);
        }
      }
  }
}

// ---------------- K2: scores + softmax + attn write (no-max, 2 passes) ------
// Swapped mfma(K,Q): D[row=k][col=q]; per-lane partial exp-sum over its k
// subset, one 2-step shfl reduce. Scores bounded (|S|<~30) so exp() is safe.
__global__ __launch_bounds__(256) void k_attn(
    const short* __restrict__ QsH, const short* __restrict__ QsL,
    const short* __restrict__ KsH, const short* __restrict__ KsL,
    float* __restrict__ attn) {
  const int lane = threadIdx.x & 63, w = threadIdx.x >> 6;
  const int col = lane & 15, g = lane >> 4;
  const int bh = blockIdx.y;
  const int q0 = blockIdx.x * 64 + w * 16;
  const size_t base = (size_t)bh * 1024 * 64;

  size_t qoff = base + (size_t)(q0 + col) * 64 + g * 8;
  bf16x8 qh0 = *(const bf16x8*)(QsH + qoff);
  bf16x8 qh1 = *(const bf16x8*)(QsH + qoff + 32);
  bf16x8 ql0 = *(const bf16x8*)(QsL + qoff);
  bf16x8 ql1 = *(const bf16x8*)(QsL + qoff + 32);

  f32x4 zero = {0.f, 0.f, 0.f, 0.f};
  float sum = 0.f;

  for (int kc = 0; kc < 64; ++kc) {
    size_t koff = base + (size_t)(kc * 16 + col) * 64 + g * 8;
    bf16x8 kh0 = *(const bf16x8*)(KsH + koff);
    bf16x8 kh1 = *(const bf16x8*)(KsH + koff + 32);
    bf16x8 kl0 = *(const bf16x8*)(KsL + koff);
    bf16x8 kl1 = *(const bf16x8*)(KsL + koff + 32);
    f32x4 S = zero;
    S = MFMA16(kh0, qh0, S);
    S = MFMA16(kh1, qh1, S);
    S = MFMA16(kl0, qh0, S);
    S = MFMA16(kl1, qh1, S);
    S = MFMA16(kh0, ql0, S);
    S = MFMA16(kh1, ql1, S);
    sum += __expf(S[0] * 0.5f) + __expf(S[1] * 0.5f) +
           __expf(S[2] * 0.5f) + __expf(S[3] * 0.5f);
  }
  sum += __shfl_xor(sum, 16);
  sum += __shfl_xor(sum, 32);
  float inv = 1.f / sum;

  float* ob = attn + (size_t)bh * 1024 * 1024 + (size_t)(q0 + col) * 1024;
  for (int kc = 0; kc < 64; ++kc) {
    size_t koff = base + (size_t)(kc * 16 + col) * 64 + g * 8;
    bf16x8 kh0 = *(const bf16x8*)(KsH + koff);
    bf16x8 kh1 = *(const bf16x8*)(KsH + koff + 32);
    bf16x8 kl0 = *(const bf16x8*)(KsL + koff);
    bf16x8 kl1 = *(const bf16x8*)(KsL + koff + 32);
    f32x4 S = zero;
    S = MFMA16(kh0, qh0, S);
    S = MFMA16(kh1, qh1, S);
    S = MFMA16(kl0, qh0, S);
    S = MFMA16(kl1, qh1, S);
    S = MFMA16(kh0, ql0, S);
    S = MFMA16(kh1, ql1, S);
    f32x4 o;
#pragma unroll
    for (int r = 0; r < 4; ++r) o[r] = __expf(S[r] * 0.5f) * inv;
    *(f32x4*)(ob + kc * 16 + g * 4) = o;
  }
}

// ---------------- K3: context = attn^T @ V (sum over q) ---------------------
__global__ __launch_bounds__(256) void k_ctx(
    const float* __restrict__ attn, const short* __restrict__ Vt,
    short* __restrict__ ctx) {
  const int lane = threadIdx.x & 63, w = threadIdx.x >> 6;
  const int col = lane & 15, g = lane >> 4;
  const int bh = blockIdx.y;
  const int k0 = blockIdx.x * 64 + w * 16;
  const float* ab = attn + (size_t)bh * 1024 * 1024;
  const short* vb = Vt + (size_t)bh * 64 * 1024;

  f32x4 zero = {0.f, 0.f, 0.f, 0.f};
  f32x4 acc[4] = {zero, zero, zero, zero};

  for (int qc = 0; qc < 32; ++qc) {
    const float* ap = ab + (size_t)(qc * 32 + g * 8) * 1024 + k0 + col;
    bf16x8 af;
#pragma unroll
    for (int j = 0; j < 8; ++j) af[j] = f2bf(ap[(size_t)j * 1024]);
#pragma unroll
    for (int nt = 0; nt < 4; ++nt) {
      bf16x8 bfv = *(const bf16x8*)(vb + (size_t)(nt * 16 + col) * 1024 + qc * 32 + g * 8);
      acc[nt] = MFMA16(af, bfv, acc[nt]);
    }
  }
  int b = bh >> 3, h = bh & 7;
#pragma unroll
  for (int nt = 0; nt < 4; ++nt)
#pragma unroll
    for (int r = 0; r < 4; ++r) {
      int kk = k0 + g * 4 + r;
      ctx[((size_t)(b * 1024 + kk)) * 512 + h * 64 + nt * 16 + col] = f2bf(acc[nt][r]);
    }
}

// ---------------- K4: output = ctx @ wp^T + bp ------------------------------
__global__ __launch_bounds__(256) void k_out(
    const short* __restrict__ ctx, const short* __restrict__ WPH,
    const float* __restrict__ bp, float* __restrict__ out) {
  const int lane = threadIdx.x & 63, w = threadIdx.x >> 6;
  const int col = lane & 15, g = lane >> 4;
  const int m0 = blockIdx.x * 64 + w * 16;

  f32x4 zero = {0.f, 0.f, 0.f, 0.f};
  f32x4 acc[4] = {zero, zero, zero, zero};

  for (int kc = 0; kc < 16; ++kc) {
    bf16x8 a = *(const bf16x8*)(ctx + (size_t)(m0 + col) * 512 + kc * 32 + g * 8);
#pragma unroll
    for (int nt = 0; nt < 4; ++nt) {
      bf16x8 bfr = *(const bf16x8*)(WPH + (size_t)(nt * 16 + col) * 512 + kc * 32 + g * 8);
      acc[nt] = MFMA16(a, bfr, acc[nt]);
    }
  }
#pragma unroll
  for (int nt = 0; nt < 4; ++nt) {
    float bias = bp[nt * 16 + col];
#pragma unroll
    for (int r = 0; r < 4; ++r)
      out[(size_t)(m0 + g * 4 + r) * 64 + nt * 16 + col] = acc[nt][r] + bias;
  }
}

extern "C" void kernel_launch(void* const* d_in, const int* in_sizes, int n_in,
                              void* d_out, int out_size, void* d_ws, size_t ws_size,
                              hipStream_t stream) {
  const float* q  = (const float*)d_in[0];
  const float* k  = (const float*)d_in[1];
  const float* v  = (const float*)d_in[2];
  const float* wq = (const float*)d_in[3];
  const float* bq = (const float*)d_in[4];
  const float* wk = (const float*)d_in[5];
  const float* bk = (const float*)d_in[6];
  const float* wv = (const float*)d_in[7];
  const float* bv = (const float*)d_in[8];
  const float* wp = (const float*)d_in[9];
  const float* bp = (const float*)d_in[10];

  float* out  = (float*)d_out;            // (4,1024,64)
  float* attn = out + 262144;             // (4,8,1024,1024)

  // workspace (shorts), with sequential-launch aliasing (~32 MB total):
  short* S = (short*)d_ws;
  const size_t E = 2097152;               // shorts per 4096x512 array
  short* XqH = S;                         // } inputs to proj_q
  short* XqL = S + E;
  short* XkH = S + 2 * E;                 // } inputs to proj_k
  short* XkL = S + 3 * E;
  short* XvH = S + 4 * E;                 //   input to proj_v
  short* QsH = S + 5 * E;
  short* QsL = S + 6 * E;
  short* KsH = S;                         // alias XqH (dead after proj_q)
  short* KsL = S + E;                     // alias XqL
  short* Vt  = S + 2 * E;                 // alias XkH (dead after proj_k)
  short* ctx = S + 3 * E;                 // alias XkL (dead after proj_v)
  short* W   = S + 7 * E;                 // [WqH|WqL|WkH|WkL|WvH], 5*NW
  short* WPH = W + 5 * (size_t)NW;        // [64][512]

  k_wconv<<<dim3(3200), dim3(256), 0, stream>>>(wq, wk, wv, wp, W, WPH);
  k_xconv<<<dim3(3072), dim3(256), 0, stream>>>(q, k, v, XqH, XqL, XkH, XkL, XvH);
  k_proj <<<dim3(8, 64), dim3(256), 0, stream>>>(XqH, XqL, W, W + NW, bq,
                                                 QsH, QsL, nullptr, 0);
  k_proj <<<dim3(8, 64), dim3(256), 0, stream>>>(XkH, XkL, W + 2 * NW, W + 3 * NW, bk,
                                                 KsH, KsL, nullptr, 0);
  k_proj <<<dim3(8, 64), dim3(256), 0, stream>>>(XvH, XvH, W + 4 * NW, W + 4 * NW, bv,
                                                 nullptr, nullptr, Vt, 1);
  k_attn <<<dim3(16, 32), dim3(256), 0, stream>>>(QsH, QsL, KsH, KsL, attn);
  k_ctx  <<<dim3(16, 32), dim3(256), 0, stream>>>(attn, Vt, ctx);
  k_out  <<<dim3(64), dim3(256), 0, stream>>>(ctx, WPH, bp, out);
}

// Round 4
// 305.786 us; speedup vs baseline: 1.2392x; 1.2020x over previous
//
#include <hip/hip_runtime.h>

// B=4, H=8, L=1024, D=64, QDIM=512.
#define QD 512
#define NW (512*512)  // elements per weight matrix

typedef __attribute__((ext_vector_type(8))) short bf16x8;  // 8 bf16
typedef __attribute__((ext_vector_type(4))) short bf16x4;  // 4 bf16
typedef __attribute__((ext_vector_type(4))) float f32x4;

#define MFMA16(a,b,c) __builtin_amdgcn_mfma_f32_16x16x32_bf16((a),(b),(c),0,0,0)

static __device__ __forceinline__ short f2bf(float f) {  // RNE float->bf16
  unsigned u = __float_as_uint(f);
  u += 0x7fffu + ((u >> 16) & 1u);
  return (short)(u >> 16);
}
static __device__ __forceinline__ float bf2f(short s) {
  return __uint_as_float(((unsigned)(unsigned short)s) << 16);
}
static __device__ __forceinline__ unsigned pk2(float a, float b) {
  return (unsigned)(unsigned short)f2bf(a) | (((unsigned)(unsigned short)f2bf(b)) << 16);
}

#define GL2LDS16(g, l)                                                        \
  __builtin_amdgcn_global_load_lds(                                           \
      (const __attribute__((address_space(1))) unsigned int*)(g),             \
      (__attribute__((address_space(3))) unsigned int*)(l), 16, 0, 0)

// ---------------- K0: weights -> bf16 (hi/lo for wq,wk; hi for wv,wp) -------
__global__ __launch_bounds__(256) void k_wconv(
    const float* __restrict__ wq, const float* __restrict__ wk,
    const float* __restrict__ wv, const float* __restrict__ wp,
    short* __restrict__ W, short* __restrict__ WPH) {
  int i = blockIdx.x * 256 + threadIdx.x;
  if (i < NW) {
    float f = wq[i]; short h = f2bf(f);
    W[i] = h; W[NW + i] = f2bf(f - bf2f(h));
  } else if (i < 2 * NW) {
    int j = i - NW;
    float f = wk[j]; short h = f2bf(f);
    W[2 * NW + j] = h; W[3 * NW + j] = f2bf(f - bf2f(h));
  } else if (i < 3 * NW) {
    int j = i - 2 * NW;
    W[4 * NW + j] = f2bf(wv[j]);
  } else {
    int j = i - 3 * NW;
    if (j < 64 * QD) WPH[j] = f2bf(wp[j]);
  }
}

// ---------------- K0b: activations -> bf16 (hi/lo for q,k; hi for v) --------
__global__ __launch_bounds__(256) void k_xconv(
    const float* __restrict__ q, const float* __restrict__ k, const float* __restrict__ v,
    short* __restrict__ XqH, short* __restrict__ XqL,
    short* __restrict__ XkH, short* __restrict__ XkL, short* __restrict__ XvH) {
  int i = blockIdx.x * 256 + threadIdx.x;   // one group of 8 floats
  int t = i >> 18;
  int j = i & 0x3FFFF;
  const float* src = t == 0 ? q : (t == 1 ? k : v);
  f32x4 x0 = *(const f32x4*)(src + (size_t)j * 8);
  f32x4 x1 = *(const f32x4*)(src + (size_t)j * 8 + 4);
  bf16x8 H, L;
#pragma unroll
  for (int jj = 0; jj < 4; ++jj) {
    short h0 = f2bf(x0[jj]); H[jj] = h0; L[jj] = f2bf(x0[jj] - bf2f(h0));
    short h1 = f2bf(x1[jj]); H[jj + 4] = h1; L[jj + 4] = f2bf(x1[jj] - bf2f(h1));
  }
  if (t == 0)      { *(bf16x8*)(XqH + (size_t)j * 8) = H; *(bf16x8*)(XqL + (size_t)j * 8) = L; }
  else if (t == 1) { *(bf16x8*)(XkH + (size_t)j * 8) = H; *(bf16x8*)(XkL + (size_t)j * 8) = L; }
  else             { *(bf16x8*)(XvH + (size_t)j * 8) = H; }
}

// ---------------- K1: projection GEMM, LDS-staged, split-bf16 ---------------
// C(4096x512) = (X @ W^T + bias) * scale. mode 0: hi/lo -> [b,h,l,d];
// mode 1 (V): bf16 -> [b,h,d,l].
__global__ __launch_bounds__(256) void k_proj(
    const short* __restrict__ XH, const short* __restrict__ XL,
    const short* __restrict__ WH, const short* __restrict__ WL,
    const float* __restrict__ bias,
    short* __restrict__ outH, short* __restrict__ outL,
    short* __restrict__ Vt, int mode, float scale) {
  __shared__ __align__(16) short Ah[64 * 32], Al[64 * 32], Bh[64 * 32], Bl[64 * 32];
  const int tid = threadIdx.x;
  const int lane = tid & 63;
  const int col = lane & 15, g = lane >> 4;
  const int w = tid >> 6, wr = w >> 1, wc = w & 1;
  const int h = blockIdx.x;
  const int m0 = blockIdx.y * 64;
  const int srow = tid >> 2;
  const int scol = ((tid & 3) ^ (srow & 3)) * 8;
  const size_t xrow = (size_t)(m0 + srow) * QD + scol;
  const size_t wrow = (size_t)(h * 64 + srow) * QD + scol;

  f32x4 zero = {0.f, 0.f, 0.f, 0.f};
  f32x4 acc[2][2] = {{zero, zero}, {zero, zero}};

  for (int kc = 0; kc < 16; ++kc) {
    const int kb = kc * 32;
    GL2LDS16(XH + xrow + kb, &Ah[tid * 8]);
    GL2LDS16(WH + wrow + kb, &Bh[tid * 8]);
    if (mode == 0) {
      GL2LDS16(XL + xrow + kb, &Al[tid * 8]);
      GL2LDS16(WL + wrow + kb, &Bl[tid * 8]);
    }
    __syncthreads();

    bf16x8 a_h[2], a_l[2], b_h[2], b_l[2];
#pragma unroll
    for (int mt = 0; mt < 2; ++mt) {
      int rowa = wr * 32 + mt * 16 + col;
      int off = rowa * 32 + ((g ^ (rowa & 3)) * 8);
      a_h[mt] = *(const bf16x8*)&Ah[off];
      if (mode == 0) a_l[mt] = *(const bf16x8*)&Al[off];
    }
#pragma unroll
    for (int nt = 0; nt < 2; ++nt) {
      int rowb = wc * 32 + nt * 16 + col;
      int off = rowb * 32 + ((g ^ (rowb & 3)) * 8);
      b_h[nt] = *(const bf16x8*)&Bh[off];
      if (mode == 0) b_l[nt] = *(const bf16x8*)&Bl[off];
    }
#pragma unroll
    for (int mt = 0; mt < 2; ++mt)
#pragma unroll
      for (int nt = 0; nt < 2; ++nt) {
        acc[mt][nt] = MFMA16(a_h[mt], b_h[nt], acc[mt][nt]);
        if (mode == 0) {
          acc[mt][nt] = MFMA16(a_l[mt], b_h[nt], acc[mt][nt]);
          acc[mt][nt] = MFMA16(a_h[mt], b_l[nt], acc[mt][nt]);
        }
      }
    __syncthreads();
  }

#pragma unroll
  for (int nt = 0; nt < 2; ++nt) {
    int d = wc * 32 + nt * 16 + col;
    float bias_v = bias[h * 64 + d];
#pragma unroll
    for (int mt = 0; mt < 2; ++mt)
#pragma unroll
      for (int r = 0; r < 4; ++r) {
        int m = m0 + wr * 32 + mt * 16 + g * 4 + r;
        int b = m >> 10, l = m & 1023;
        float val = (acc[mt][nt][r] + bias_v) * scale;
        if (mode == 0) {
          size_t idx = (((size_t)b * 8 + h) * 1024 + l) * 64 + d;
          short hh = f2bf(val);
          outH[idx] = hh;
          outL[idx] = f2bf(val - bf2f(hh));
        } else {
          Vt[(((size_t)b * 8 + h) * 64 + d) * 1024 + l] = f2bf(val);
        }
      }
  }
}

// ---------------- K2: row sums of exp(S) (1-term bf16, K staged in LDS) -----
// mfma(K,Q): D[row=k][col=q]; per-lane partial sum over its k subset.
// Q already carries the 0.5 score scale (folded into k_proj).
__global__ __launch_bounds__(256) void k_sums(
    const short* __restrict__ QsH, const short* __restrict__ KsH,
    float* __restrict__ invp) {
  __shared__ __align__(16) short KL[32 * 64];  // 32 k-rows x 64 d
  const int tid = threadIdx.x;
  const int lane = tid & 63, w = tid >> 6;
  const int col = lane & 15, g = lane >> 4;
  int wgid = blockIdx.x + gridDim.x * blockIdx.y;     // XCD-aware swizzle
  int nid = (wgid & 7) * 64 + (wgid >> 3);
  const int qblk = nid & 15, bh = nid >> 4;
  const int q0 = qblk * 64 + w * 16;
  const size_t base = (size_t)bh * 65536;

  const short* qp = QsH + base + (size_t)(q0 + col) * 64 + g * 8;
  bf16x8 qB0 = *(const bf16x8*)qp;
  bf16x8 qB1 = *(const bf16x8*)(qp + 32);

  const int srow = tid >> 3, sslot = tid & 7;
  const short* ksrc = KsH + base + (size_t)srow * 64 + ((sslot ^ (srow & 7)) * 8);

  f32x4 zero = {0.f, 0.f, 0.f, 0.f};
  float sum = 0.f;
  for (int kb = 0; kb < 32; ++kb) {
    GL2LDS16(ksrc + kb * 2048, &KL[tid * 8]);
    __syncthreads();
#pragma unroll
    for (int sub = 0; sub < 2; ++sub) {
      const short* lb = &KL[(sub * 16 + col) * 64];
      bf16x8 ka0 = *(const bf16x8*)(lb + ((g ^ (col & 7)) * 8));
      bf16x8 ka1 = *(const bf16x8*)(lb + (((4 + g) ^ (col & 7)) * 8));
      f32x4 S = zero;
      S = MFMA16(ka0, qB0, S);
      S = MFMA16(ka1, qB1, S);
      sum += __expf(S[0]) + __expf(S[1]) + __expf(S[2]) + __expf(S[3]);
    }
    __syncthreads();
  }
  sum += __shfl_xor(sum, 16);
  sum += __shfl_xor(sum, 32);
  if (lane < 16) invp[bh * 1024 + q0 + col] = 1.f / sum;
}

// ---------------- K3: fused attn write + context ----------------------------
// mfma(Q,K): D[row=q][col=k] -> P has lane-col=k = exactly the PV A-frag
// lane mapping. PV B-operand reads V in the q-permutation matching P's
// natural register order (no shuffles). Wave owns 16 k, sweeps all q.
__global__ __launch_bounds__(256) void k_pv(
    const short* __restrict__ QsH, const short* __restrict__ QsL,
    const short* __restrict__ KsH, const short* __restrict__ KsL,
    const short* __restrict__ Vt, const float* __restrict__ invp,
    float* __restrict__ attn, short* __restrict__ ctx) {
  __shared__ __align__(16) short QH[32 * 64], QL[32 * 64];  // 4 KB each
  const int tid = threadIdx.x;
  const int lane = tid & 63, w = tid >> 6;
  const int col = lane & 15, g = lane >> 4;
  int wgid = blockIdx.x + gridDim.x * blockIdx.y;     // XCD-aware swizzle
  int nid = (wgid & 7) * 64 + (wgid >> 3);
  const int kblk = nid & 15, bh = nid >> 4;
  const int k0 = kblk * 64 + w * 16;
  const size_t base = (size_t)bh * 65536;

  // K fragments (B-operand), fixed for the whole kernel: rows k0+col.
  const short* kp = KsH + base + (size_t)(k0 + col) * 64 + g * 8;
  bf16x8 khB0 = *(const bf16x8*)kp;
  bf16x8 khB1 = *(const bf16x8*)(kp + 32);
  const short* kpl = KsL + base + (size_t)(k0 + col) * 64 + g * 8;
  bf16x8 klB0 = *(const bf16x8*)kpl;
  bf16x8 klB1 = *(const bf16x8*)(kpl + 32);

  const short* vb = Vt + base;                     // [64][1024]
  float* ab = attn + (size_t)bh * 1024 * 1024;
  const float* invB = invp + bh * 1024;

  const int srow = tid >> 3, sslot = tid & 7;
  const size_t qsrc = base + (size_t)srow * 64 + ((sslot ^ (srow & 7)) * 8);

  f32x4 zero = {0.f, 0.f, 0.f, 0.f};
  f32x4 O[4] = {zero, zero, zero, zero};

  for (int cc = 0; cc < 32; ++cc) {
    GL2LDS16(QsH + qsrc + cc * 2048, &QH[tid * 8]);
    GL2LDS16(QsL + qsrc + cc * 2048, &QL[tid * 8]);
    __syncthreads();

    float p[2][4];
#pragma unroll
    for (int t = 0; t < 2; ++t) {
      const short* lh = &QH[(t * 16 + col) * 64];
      const short* ll = &QL[(t * 16 + col) * 64];
      int o0 = (g ^ (col & 7)) * 8, o1 = ((4 + g) ^ (col & 7)) * 8;
      bf16x8 qh0 = *(const bf16x8*)(lh + o0);
      bf16x8 qh1 = *(const bf16x8*)(lh + o1);
      bf16x8 ql0 = *(const bf16x8*)(ll + o0);
      bf16x8 ql1 = *(const bf16x8*)(ll + o1);
      f32x4 S = zero;
      S = MFMA16(qh0, khB0, S);
      S = MFMA16(qh1, khB1, S);
      S = MFMA16(ql0, khB0, S);
      S = MFMA16(ql1, khB1, S);
      S = MFMA16(qh0, klB0, S);
      S = MFMA16(qh1, klB1, S);
      f32x4 iv = *(const f32x4*)(invB + cc * 32 + t * 16 + 4 * g);
      float* ap = ab + (size_t)(cc * 32 + t * 16 + 4 * g) * 1024 + k0 + col;
#pragma unroll
      for (int r = 0; r < 4; ++r) {
        p[t][r] = __expf(S[r]) * iv[r];
        ap[(size_t)r * 1024] = p[t][r];
      }
    }
    // Pack P as the PV A-fragment (q-slots: j=0..3 -> tile0 q=4g+j,
    // j=4..7 -> tile1 q=16+4g+j-4) and read V in the same q-permutation.
    union { bf16x8 v; unsigned u[4]; } pa;
    pa.u[0] = pk2(p[0][0], p[0][1]); pa.u[1] = pk2(p[0][2], p[0][3]);
    pa.u[2] = pk2(p[1][0], p[1][1]); pa.u[3] = pk2(p[1][2], p[1][3]);
#pragma unroll
    for (int dt = 0; dt < 4; ++dt) {
      const short* vr = vb + (size_t)(dt * 16 + col) * 1024 + cc * 32 + 4 * g;
      union { bf16x8 v; bf16x4 h[2]; } vf;
      vf.h[0] = *(const bf16x4*)vr;
      vf.h[1] = *(const bf16x4*)(vr + 16);
      O[dt] = MFMA16(pa.v, vf.v, O[dt]);
    }
    __syncthreads();
  }

  int b = bh >> 3, h = bh & 7;
#pragma unroll
  for (int dt = 0; dt < 4; ++dt)
#pragma unroll
    for (int r = 0; r < 4; ++r) {
      int kk = k0 + 4 * g + r;
      ctx[((size_t)(b * 1024 + kk)) * 512 + h * 64 + dt * 16 + col] = f2bf(O[dt][r]);
    }
}

// ---------------- K4: output = ctx @ wp^T + bp ------------------------------
__global__ __launch_bounds__(256) void k_out(
    const short* __restrict__ ctx, const short* __restrict__ WPH,
    const float* __restrict__ bp, float* __restrict__ out) {
  const int lane = threadIdx.x & 63, w = threadIdx.x >> 6;
  const int col = lane & 15, g = lane >> 4;
  const int m0 = blockIdx.x * 64 + w * 16;

  f32x4 zero = {0.f, 0.f, 0.f, 0.f};
  f32x4 acc[4] = {zero, zero, zero, zero};

  for (int kc = 0; kc < 16; ++kc) {
    bf16x8 a = *(const bf16x8*)(ctx + (size_t)(m0 + col) * 512 + kc * 32 + g * 8);
#pragma unroll
    for (int nt = 0; nt < 4; ++nt) {
      bf16x8 bfr = *(const bf16x8*)(WPH + (size_t)(nt * 16 + col) * 512 + kc * 32 + g * 8);
      acc[nt] = MFMA16(a, bfr, acc[nt]);
    }
  }
#pragma unroll
  for (int nt = 0; nt < 4; ++nt) {
    float bias = bp[nt * 16 + col];
#pragma unroll
    for (int r = 0; r < 4; ++r)
      out[(size_t)(m0 + g * 4 + r) * 64 + nt * 16 + col] = acc[nt][r] + bias;
  }
}

extern "C" void kernel_launch(void* const* d_in, const int* in_sizes, int n_in,
                              void* d_out, int out_size, void* d_ws, size_t ws_size,
                              hipStream_t stream) {
  const float* q  = (const float*)d_in[0];
  const float* k  = (const float*)d_in[1];
  const float* v  = (const float*)d_in[2];
  const float* wq = (const float*)d_in[3];
  const float* bq = (const float*)d_in[4];
  const float* wk = (const float*)d_in[5];
  const float* bk = (const float*)d_in[6];
  const float* wv = (const float*)d_in[7];
  const float* bv = (const float*)d_in[8];
  const float* wp = (const float*)d_in[9];
  const float* bp = (const float*)d_in[10];

  float* out  = (float*)d_out;            // (4,1024,64)
  float* attn = out + 262144;             // (4,8,1024,1024)

  // workspace (shorts), sequential-launch aliasing (~32.3 MB total):
  short* S = (short*)d_ws;
  const size_t E = 2097152;               // shorts per 4096x512 array
  short* XqH = S;
  short* XqL = S + E;
  short* XkH = S + 2 * E;
  short* XkL = S + 3 * E;
  short* XvH = S + 4 * E;
  short* QsH = S + 5 * E;
  short* QsL = S + 6 * E;
  short* KsH = S;                         // alias XqH (dead after proj_q)
  short* KsL = S + E;                     // alias XqL
  short* Vt  = S + 2 * E;                 // alias XkH (dead after proj_k)
  short* ctx = S + 3 * E;                 // alias XkL (dead after proj_v)
  short* W   = S + 7 * E;                 // [WqH|WqL|WkH|WkL|WvH]
  short* WPH = W + 5 * (size_t)NW;        // [64][512]
  float* invp = (float*)(WPH + 64 * QD);  // [32][1024] f32 (128 KB)

  k_wconv<<<dim3(3200), dim3(256), 0, stream>>>(wq, wk, wv, wp, W, WPH);
  k_xconv<<<dim3(3072), dim3(256), 0, stream>>>(q, k, v, XqH, XqL, XkH, XkL, XvH);
  k_proj <<<dim3(8, 64), dim3(256), 0, stream>>>(XqH, XqL, W, W + NW, bq,
                                                 QsH, QsL, nullptr, 0, 0.5f);
  k_proj <<<dim3(8, 64), dim3(256), 0, stream>>>(XkH, XkL, W + 2 * NW, W + 3 * NW, bk,
                                                 KsH, KsL, nullptr, 0, 1.0f);
  k_proj <<<dim3(8, 64), dim3(256), 0, stream>>>(XvH, XvH, W + 4 * NW, W + 4 * NW, bv,
                                                 nullptr, nullptr, Vt, 1, 1.0f);
  k_sums <<<dim3(16, 32), dim3(256), 0, stream>>>(QsH, KsH, invp);
  k_pv   <<<dim3(16, 32), dim3(256), 0, stream>>>(QsH, QsL, KsH, KsL, Vt, invp,
                                                  attn, ctx);
  k_out  <<<dim3(64), dim3(256), 0, stream>>>(ctx, WPH, bp, out);
}